// Round 14
// baseline (270.983 us; speedup 1.0000x reference)
//
#include <hip/hip_runtime.h>
#include <math.h>

#define D_MODEL 1024
#define N_HEADS 16
#define D_HEAD  64
#define LSR_RANK 32
#define BATCH 2
#define SEQ 2048
#define M_TOT (BATCH*SEQ)

typedef __attribute__((ext_vector_type(8))) short short8v;
typedef __attribute__((ext_vector_type(4))) float f32x4;

static __device__ __forceinline__ ushort bfhi(float f) {
    union { float f; unsigned u; } c; c.f = f;
    return (ushort)(c.u >> 16);
}
static __device__ __forceinline__ float bff(ushort h) {
    union { unsigned u; float f; } c; c.u = ((unsigned)h) << 16;
    return c.f;
}
static __device__ __forceinline__ ushort f2bf_rn(float f) {
    union { float f; unsigned u; } c; c.f = f;
    unsigned r = c.u + 0x7FFF + ((c.u >> 16) & 1);
    return (ushort)(r >> 16);
}
static __device__ __forceinline__ void split8(const float4 a, const float4 b,
                                              short8v& h, short8v& l) {
    ushort h0 = bfhi(a.x), h1 = bfhi(a.y), h2 = bfhi(a.z), h3 = bfhi(a.w);
    ushort h4 = bfhi(b.x), h5 = bfhi(b.y), h6 = bfhi(b.z), h7 = bfhi(b.w);
    h[0] = (short)h0; h[1] = (short)h1; h[2] = (short)h2; h[3] = (short)h3;
    h[4] = (short)h4; h[5] = (short)h5; h[6] = (short)h6; h[7] = (short)h7;
    l[0] = (short)bfhi(a.x - bff(h0)); l[1] = (short)bfhi(a.y - bff(h1));
    l[2] = (short)bfhi(a.z - bff(h2)); l[3] = (short)bfhi(a.w - bff(h3));
    l[4] = (short)bfhi(b.x - bff(h4)); l[5] = (short)bfhi(b.y - bff(h5));
    l[6] = (short)bfhi(b.z - bff(h6)); l[7] = (short)bfhi(b.w - bff(h7));
}

// ---------------------------------------------------------------------------
// Weff_tmp[k][base+c] = sum_d W[k, h*64+d] * Wlsr[h, d, r]
// ---------------------------------------------------------------------------
__global__ __launch_bounds__(256) void eff_weight_kernel(
    const float* __restrict__ W, const float* __restrict__ Wlsr,
    float* __restrict__ Weff_tmp, int base)
{
    int idx = blockIdx.x * 256 + threadIdx.x;
    int k = idx >> 9;
    int c = idx & 511;
    int h = c >> 5;
    int r = c & 31;
    const float* wrow = W + (size_t)k * D_MODEL + h * D_HEAD;
    const float* lsr  = Wlsr + (size_t)h * D_HEAD * LSR_RANK + r;
    float acc = 0.f;
    #pragma unroll
    for (int d = 0; d < D_HEAD; ++d)
        acc = fmaf(wrow[d], lsr[d * LSR_RANK], acc);
    Weff_tmp[(size_t)k * 1024 + base + c] = acc;
}

__global__ __launch_bounds__(256) void eff_bias_kernel(
    const float* __restrict__ bq, const float* __restrict__ Wq_lsr,
    const float* __restrict__ bk, const float* __restrict__ Wk_lsr,
    const float* __restrict__ bv, float* __restrict__ bcat)
{
    int c = blockIdx.x * 256 + threadIdx.x;
    if (c < 1024) {
        const float* bias = (c < 512) ? bq : bk;
        const float* lsr  = (c < 512) ? Wq_lsr : Wk_lsr;
        int cc = c & 511;
        int h = cc >> 5, r = cc & 31;
        float acc = 0.f;
        #pragma unroll
        for (int d = 0; d < D_HEAD; ++d)
            acc = fmaf(bias[h * D_HEAD + d],
                       lsr[(size_t)h * D_HEAD * LSR_RANK + d * LSR_RANK + r], acc);
        bcat[c] = acc;
    } else {
        bcat[c] = bv[c - 1024];
    }
}

// ---------------------------------------------------------------------------
// 1024x1024 fp32 transpose
// ---------------------------------------------------------------------------
__global__ __launch_bounds__(256) void transpose1024(
    const float* __restrict__ in, float* __restrict__ out)
{
    __shared__ float t[64][65];
    const int tid = threadIdx.x;
    const int r0 = blockIdx.y * 64, c0 = blockIdx.x * 64;
    const int tr = tid >> 4, tc = tid & 15;
    #pragma unroll
    for (int i = 0; i < 4; ++i) {
        float4 v = *(const float4*)&in[(size_t)(r0 + tr + i * 16) * 1024 + c0 + tc * 4];
        t[tr + i * 16][tc * 4 + 0] = v.x;
        t[tr + i * 16][tc * 4 + 1] = v.y;
        t[tr + i * 16][tc * 4 + 2] = v.z;
        t[tr + i * 16][tc * 4 + 3] = v.w;
    }
    __syncthreads();
    #pragma unroll
    for (int i = 0; i < 4; ++i) {
        float4 v;
        v.x = t[tc * 4 + 0][tr + i * 16];
        v.y = t[tc * 4 + 1][tr + i * 16];
        v.z = t[tc * 4 + 2][tr + i * 16];
        v.w = t[tc * 4 + 3][tr + i * 16];
        *(float4*)&out[(size_t)(c0 + tr + i * 16) * 1024 + r0 + tc * 4] = v;
    }
}

// ---------------------------------------------------------------------------
// Split-bf16 MFMA GEMM (r9/r10-validated), 128x128 tile, BK=32.
// ---------------------------------------------------------------------------
__global__ __launch_bounds__(256) void gemm_bt_split(
    const float* __restrict__ A,
    const float* __restrict__ Bt,
    const float* __restrict__ bias,
    float* __restrict__ C0, float* __restrict__ C1, int csplit)
{
    __shared__ __align__(16) short Ah[128 * 40], Al[128 * 40];
    __shared__ __align__(16) short Bh[128 * 40], Bl[128 * 40];

    const int tid = threadIdx.x;
    const int m0 = blockIdx.y * 128, n0 = blockIdx.x * 128;
    const int wid = tid >> 6, wr = wid >> 1, wc = wid & 1;
    const int lane = tid & 63, fr = lane & 15, fq = lane >> 4;
    const int srow = tid >> 1;
    const int skq  = (tid & 1) << 4;

    float* Cw; int ncol;
    if (n0 < csplit) { Cw = C0; ncol = n0; }
    else             { Cw = C1; ncol = n0 - csplit; }

    f32x4 acc[4][4];
    #pragma unroll
    for (int i = 0; i < 4; ++i)
        #pragma unroll
        for (int j = 0; j < 4; ++j)
            acc[i][j] = (f32x4){0.f, 0.f, 0.f, 0.f};

    const float* Ag = A + (size_t)(m0 + srow) * 1024 + skq;
    const float* Bg = Bt + (size_t)(n0 + srow) * 1024 + skq;
    short* pAh = &Ah[srow * 40 + skq];
    short* pAl = &Al[srow * 40 + skq];
    short* pBh = &Bh[srow * 40 + skq];
    short* pBl = &Bl[srow * 40 + skq];

    for (int k0 = 0; k0 < 1024; k0 += 32) {
        float4 a0 = *(const float4*)(Ag + k0);
        float4 a1 = *(const float4*)(Ag + k0 + 4);
        float4 a2 = *(const float4*)(Ag + k0 + 8);
        float4 a3 = *(const float4*)(Ag + k0 + 12);
        float4 b0 = *(const float4*)(Bg + k0);
        float4 b1 = *(const float4*)(Bg + k0 + 4);
        float4 b2 = *(const float4*)(Bg + k0 + 8);
        float4 b3 = *(const float4*)(Bg + k0 + 12);
        short8v h, l;
        split8(a0, a1, h, l);
        *(short8v*)pAh = h;  *(short8v*)pAl = l;
        split8(a2, a3, h, l);
        *(short8v*)(pAh + 8) = h;  *(short8v*)(pAl + 8) = l;
        split8(b0, b1, h, l);
        *(short8v*)pBh = h;  *(short8v*)pBl = l;
        split8(b2, b3, h, l);
        *(short8v*)(pBh + 8) = h;  *(short8v*)(pBl + 8) = l;
        __syncthreads();

        short8v afh[4], afl[4], bfh[4], bfl[4];
        #pragma unroll
        for (int fi = 0; fi < 4; ++fi) {
            const int ar = wr * 64 + fi * 16 + fr;
            afh[fi] = *(const short8v*)&Ah[ar * 40 + fq * 8];
            afl[fi] = *(const short8v*)&Al[ar * 40 + fq * 8];
        }
        #pragma unroll
        for (int bj = 0; bj < 4; ++bj) {
            const int br = wc * 64 + bj * 16 + fr;
            bfh[bj] = *(const short8v*)&Bh[br * 40 + fq * 8];
            bfl[bj] = *(const short8v*)&Bl[br * 40 + fq * 8];
        }
        #pragma unroll
        for (int fi = 0; fi < 4; ++fi) {
            #pragma unroll
            for (int bj = 0; bj < 4; ++bj) {
                acc[fi][bj] = __builtin_amdgcn_mfma_f32_16x16x32_bf16(
                    afh[fi], bfh[bj], acc[fi][bj], 0, 0, 0);
                acc[fi][bj] = __builtin_amdgcn_mfma_f32_16x16x32_bf16(
                    afh[fi], bfl[bj], acc[fi][bj], 0, 0, 0);
                acc[fi][bj] = __builtin_amdgcn_mfma_f32_16x16x32_bf16(
                    afl[fi], bfh[bj], acc[fi][bj], 0, 0, 0);
            }
        }
        __syncthreads();
    }

    #pragma unroll
    for (int fi = 0; fi < 4; ++fi) {
        #pragma unroll
        for (int bj = 0; bj < 4; ++bj) {
            const int r = m0 + wr * 64 + fi * 16 + fq * 4;
            const int c = ncol + wc * 64 + bj * 16 + fr;
            const float bv_ = bias[n0 - ncol + c];
            #pragma unroll
            for (int j = 0; j < 4; ++j)
                Cw[(size_t)(r + j) * 1024 + c] = acc[fi][bj][j] + bv_;
        }
    }
}

// ---------------------------------------------------------------------------
// K pre-split into B-frag-ready layout: Kth/Ktl [bh][2048 t][32 r] bf16.
// ---------------------------------------------------------------------------
__global__ __launch_bounds__(256) void kt_prep(
    const float* __restrict__ Yqk,
    short* __restrict__ Kth, short* __restrict__ Ktl)
{
    const int bh = blockIdx.x;
    const int b = bh >> 4, h = bh & 15;
    const int t0 = blockIdx.y * 128;
    const int tid = threadIdx.x;
    const int tl = tid >> 1, half = tid & 1;
    const float* src = Yqk + (size_t)(b * SEQ + t0 + tl) * 1024 + 512 + h * 32 + half * 16;
    short8v h0, l0, h1, l1;
    split8(((const float4*)src)[0], ((const float4*)src)[1], h0, l0);
    split8(((const float4*)src)[2], ((const float4*)src)[3], h1, l1);
    short* oh = Kth + ((size_t)bh * 2048 + t0 + tl) * 32 + half * 16;
    short* ol = Ktl + ((size_t)bh * 2048 + t0 + tl) * 32 + half * 16;
    *(short8v*)oh = h0;  *(short8v*)(oh + 8) = h1;
    *(short8v*)ol = l0;  *(short8v*)(ol + 8) = l1;
}

// ---------------------------------------------------------------------------
// V transpose + bf16-rn: Vtmp[4096][1024] -> Vbf [bh][64 d][2048 t]
// ---------------------------------------------------------------------------
__global__ __launch_bounds__(256) void vt_prep(
    const float* __restrict__ Vtmp, short* __restrict__ Vbf)
{
    __shared__ float t[64][68];
    const int bh = blockIdx.x;
    const int b = bh >> 4, h = bh & 15;
    const int t0 = blockIdx.y * 64;
    const int tid = threadIdx.x;
    {
        const int tl = tid >> 2, sg = tid & 3;
        const float* vp = Vtmp + (size_t)(b * SEQ + t0 + tl) * 1024 + h * 64 + sg * 16;
        #pragma unroll
        for (int i = 0; i < 4; ++i)
            *(float4*)&t[tl][sg * 16 + i * 4] = *(const float4*)(vp + i * 4);
    }
    __syncthreads();
    {
        const int d = tid >> 2, sg = tid & 3;
        short8v h0, h1;
        #pragma unroll
        for (int i = 0; i < 8; ++i) {
            h0[i] = (short)f2bf_rn(t[sg * 16 + i][d]);
            h1[i] = (short)f2bf_rn(t[sg * 16 + 8 + i][d]);
        }
        short* oh = Vbf + ((size_t)bh * 64 + d) * 2048 + t0 + sg * 16;
        *(short8v*)oh = h0;  *(short8v*)(oh + 8) = h1;
    }
}

// ---------------------------------------------------------------------------
// MFMA flash attention v5 = v4 with the load cluster forced concurrent by a
// DATA dependency. r13 lesson: sched_barrier(0) is advisory to the
// scheduler, but the serialization came from regalloc (VGPR=64 cannot hold
// 16 in-flight fragments -> s_waitcnt per register reuse). The empty asm
// consuming all 16 fragments as "+v" operands forces them simultaneously
// live -> RA must allocate ~64 VGPRs for them -> loads issue back-to-back,
// one vmcnt wait per iteration.
// ---------------------------------------------------------------------------
#define P_LD  68
#define MASKVAL (-1e30f)

__global__ __launch_bounds__(256, 2) void flash_mfma(
    const float* __restrict__ Yqk,   // [4096][1024]: q_lr(512) | k_lr(512)
    const short* __restrict__ Kth, const short* __restrict__ Ktl,
    const short* __restrict__ Vbf,   // [32][64][2048]
    float* __restrict__ O)           // [4096][1024] (B,T,H,Dh)
{
    const float scale = 0.1767766952966369f;  // 1/sqrt(32)
    const int L = blockIdx.x;
    const int bh = (L & 7) * 4 + ((L >> 3) & 3);
    const int qt = 31 - (L >> 5);              // LPT
    const int b = bh >> 4, h = bh & 15;
    const int tid = threadIdx.x;
    const int w = tid >> 6;
    const int lane = tid & 63;
    const int fr = lane & 15, fq = lane >> 4;

    __shared__ __align__(16) short Pl[4][16 * P_LD];
    short* Pw = &Pl[w][0];

    short8v aqh, aql;
    {
        const float* qp = Yqk + (size_t)(b * SEQ + qt * 64 + w * 16 + fr) * 1024
                          + h * 32 + fq * 8;
        split8(*(const float4*)qp, *(const float4*)(qp + 4), aqh, aql);
    }

    f32x4 acc0 = {0,0,0,0}, acc1 = {0,0,0,0}, acc2 = {0,0,0,0}, acc3 = {0,0,0,0};
    float m_[4], l_[4];
    #pragma unroll
    for (int r = 0; r < 4; ++r) { m_[r] = MASKVAL; l_[r] = 0.f; }

    const short* kb_h = Kth + (size_t)bh * 2048 * 32;
    const short* kb_l = Ktl + (size_t)bh * 2048 * 32;
    const short* vb   = Vbf + (size_t)bh * 64 * 2048;
    const int kidx = fr * 32 + fq * 8;
    const int vrow = fr * 2048 + fq * 8;

    for (int jt = 0; jt <= qt; ++jt) {
        // ---- load cluster ----
        const short* kp_h = kb_h + (size_t)jt * 64 * 32;
        const short* kp_l = kb_l + (size_t)jt * 64 * 32;
        short8v kh0 = *(const short8v*)&kp_h[kidx];
        short8v kh1 = *(const short8v*)&kp_h[kidx + 512];
        short8v kh2 = *(const short8v*)&kp_h[kidx + 1024];
        short8v kh3 = *(const short8v*)&kp_h[kidx + 1536];
        short8v kl0 = *(const short8v*)&kp_l[kidx];
        short8v kl1 = *(const short8v*)&kp_l[kidx + 512];
        short8v kl2 = *(const short8v*)&kp_l[kidx + 1024];
        short8v kl3 = *(const short8v*)&kp_l[kidx + 1536];
        const short* vp = vb + vrow + jt * 64;
        short8v v00 = *(const short8v*)&vp[0];
        short8v v01 = *(const short8v*)&vp[32];
        short8v v10 = *(const short8v*)&vp[16 * 2048];
        short8v v11 = *(const short8v*)&vp[16 * 2048 + 32];
        short8v v20 = *(const short8v*)&vp[32 * 2048];
        short8v v21 = *(const short8v*)&vp[32 * 2048 + 32];
        short8v v30 = *(const short8v*)&vp[48 * 2048];
        short8v v31 = *(const short8v*)&vp[48 * 2048 + 32];
        // DATA-dependency fence: all 16 fragments simultaneously live here.
        asm volatile(""
            : "+v"(kh0), "+v"(kh1), "+v"(kh2), "+v"(kh3),
              "+v"(kl0), "+v"(kl1), "+v"(kl2), "+v"(kl3),
              "+v"(v00), "+v"(v01), "+v"(v10), "+v"(v11),
              "+v"(v20), "+v"(v21), "+v"(v30), "+v"(v31));

        // ---- S = Q K^T (split-bf16) ----
        f32x4 s0 = {0,0,0,0}, s1 = {0,0,0,0}, s2 = {0,0,0,0}, s3 = {0,0,0,0};
        s0 = __builtin_amdgcn_mfma_f32_16x16x32_bf16(aqh, kh0, s0, 0, 0, 0);
        s0 = __builtin_amdgcn_mfma_f32_16x16x32_bf16(aqh, kl0, s0, 0, 0, 0);
        s0 = __builtin_amdgcn_mfma_f32_16x16x32_bf16(aql, kh0, s0, 0, 0, 0);
        s1 = __builtin_amdgcn_mfma_f32_16x16x32_bf16(aqh, kh1, s1, 0, 0, 0);
        s1 = __builtin_amdgcn_mfma_f32_16x16x32_bf16(aqh, kl1, s1, 0, 0, 0);
        s1 = __builtin_amdgcn_mfma_f32_16x16x32_bf16(aql, kh1, s1, 0, 0, 0);
        s2 = __builtin_amdgcn_mfma_f32_16x16x32_bf16(aqh, kh2, s2, 0, 0, 0);
        s2 = __builtin_amdgcn_mfma_f32_16x16x32_bf16(aqh, kl2, s2, 0, 0, 0);
        s2 = __builtin_amdgcn_mfma_f32_16x16x32_bf16(aql, kh2, s2, 0, 0, 0);
        s3 = __builtin_amdgcn_mfma_f32_16x16x32_bf16(aqh, kh3, s3, 0, 0, 0);
        s3 = __builtin_amdgcn_mfma_f32_16x16x32_bf16(aqh, kl3, s3, 0, 0, 0);
        s3 = __builtin_amdgcn_mfma_f32_16x16x32_bf16(aql, kh3, s3, 0, 0, 0);

        s0 *= scale; s1 *= scale; s2 *= scale; s3 *= scale;

        if (jt == qt) {
            #pragma unroll
            for (int r = 0; r < 4; ++r) {
                const int q_l = w * 16 + fq * 4 + r;
                s0[r] = (fr      <= q_l) ? s0[r] : MASKVAL;
                s1[r] = (16 + fr <= q_l) ? s1[r] : MASKVAL;
                s2[r] = (32 + fr <= q_l) ? s2[r] : MASKVAL;
                s3[r] = (48 + fr <= q_l) ? s3[r] : MASKVAL;
            }
        }

        float al[4];
        #pragma unroll
        for (int r = 0; r < 4; ++r) {
            float mt = fmaxf(fmaxf(s0[r], s1[r]), fmaxf(s2[r], s3[r]));
            mt = fmaxf(mt, __shfl_xor(mt, 1));
            mt = fmaxf(mt, __shfl_xor(mt, 2));
            mt = fmaxf(mt, __shfl_xor(mt, 4));
            mt = fmaxf(mt, __shfl_xor(mt, 8));
            const float mnew = fmaxf(m_[r], mt);
            al[r] = __expf(m_[r] - mnew);
            m_[r] = mnew;
            s0[r] = __expf(s0[r] - mnew);
            s1[r] = __expf(s1[r] - mnew);
            s2[r] = __expf(s2[r] - mnew);
            s3[r] = __expf(s3[r] - mnew);
            float ps = s0[r] + s1[r] + s2[r] + s3[r];
            ps += __shfl_xor(ps, 1);
            ps += __shfl_xor(ps, 2);
            ps += __shfl_xor(ps, 4);
            ps += __shfl_xor(ps, 8);
            l_[r] = l_[r] * al[r] + ps;
        }

        #pragma unroll
        for (int r = 0; r < 4; ++r) {
            const int prow = fq * 4 + r;
            Pw[prow * P_LD +      fr] = (short)f2bf_rn(s0[r]);
            Pw[prow * P_LD + 16 + fr] = (short)f2bf_rn(s1[r]);
            Pw[prow * P_LD + 32 + fr] = (short)f2bf_rn(s2[r]);
            Pw[prow * P_LD + 48 + fr] = (short)f2bf_rn(s3[r]);
        }
        #pragma unroll
        for (int r = 0; r < 4; ++r) {
            acc0[r] *= al[r]; acc1[r] *= al[r];
            acc2[r] *= al[r]; acc3[r] *= al[r];
        }
        short8v pa0 = *(const short8v*)&Pw[fr * P_LD + fq * 8];
        short8v pa1 = *(const short8v*)&Pw[fr * P_LD + 32 + fq * 8];

        acc0 = __builtin_amdgcn_mfma_f32_16x16x32_bf16(pa0, v00, acc0, 0, 0, 0);
        acc0 = __builtin_amdgcn_mfma_f32_16x16x32_bf16(pa1, v01, acc0, 0, 0, 0);
        acc1 = __builtin_amdgcn_mfma_f32_16x16x32_bf16(pa0, v10, acc1, 0, 0, 0);
        acc1 = __builtin_amdgcn_mfma_f32_16x16x32_bf16(pa1, v11, acc1, 0, 0, 0);
        acc2 = __builtin_amdgcn_mfma_f32_16x16x32_bf16(pa0, v20, acc2, 0, 0, 0);
        acc2 = __builtin_amdgcn_mfma_f32_16x16x32_bf16(pa1, v21, acc2, 0, 0, 0);
        acc3 = __builtin_amdgcn_mfma_f32_16x16x32_bf16(pa0, v30, acc3, 0, 0, 0);
        acc3 = __builtin_amdgcn_mfma_f32_16x16x32_bf16(pa1, v31, acc3, 0, 0, 0);
    }

    #pragma unroll
    for (int r = 0; r < 4; ++r) {
        const float inv = 1.f / l_[r];
        const int trow = qt * 64 + w * 16 + fq * 4 + r;
        float* op = O + (size_t)(b * SEQ + trow) * 1024 + h * 64;
        op[     fr] = acc0[r] * inv;
        op[16 + fr] = acc1[r] * inv;
        op[32 + fr] = acc2[r] * inv;
        op[48 + fr] = acc3[r] * inv;
    }
}

// ---------------------------------------------------------------------------
extern "C" void kernel_launch(void* const* d_in, const int* in_sizes, int n_in,
                              void* d_out, int out_size, void* d_ws, size_t ws_size,
                              hipStream_t stream)
{
    const float* x      = (const float*)d_in[0];
    const float* Wq     = (const float*)d_in[1];
    const float* bq     = (const float*)d_in[2];
    const float* Wk     = (const float*)d_in[3];
    const float* bk     = (const float*)d_in[4];
    const float* Wv     = (const float*)d_in[5];
    const float* bv     = (const float*)d_in[6];
    const float* Wo     = (const float*)d_in[7];
    const float* bo     = (const float*)d_in[8];
    const float* Wq_lsr = (const float*)d_in[9];
    const float* Wk_lsr = (const float*)d_in[10];
    float* out = (float*)d_out;

    // workspace (floats/shorts), ~56 MB
    float* ws     = (float*)d_ws;
    float* Wcat_t = ws;                                    // 2M f (8 MB)
    float* bcat   = Wcat_t + (size_t)2048 * 1024;          // 2048
    float* Yqk    = bcat + 2048;                           // 4M f (16 MB)
    float* Vtmp   = Yqk + (size_t)M_TOT * 1024;            // 4M f (16 MB)
    short* Vbf    = (short*)(Vtmp + (size_t)M_TOT * 1024); // 4M s (8 MB)
    short* Kth    = Vbf + (size_t)32 * 64 * 2048;          // 2M s (4 MB)
    short* Ktl    = Kth + (size_t)32 * 2048 * 32;          // 2M s (4 MB)
    float* Weff_tmp = (float*)Vbf;   // alias: dead before vt_prep writes Vbf
    float* Oacc   = Vtmp;            // alias: fp32 V dead after vt_prep
    float* Wo_t   = Wcat_t;          // alias: Wcat_t dead after proj gemm

    eff_weight_kernel<<<2048, 256, 0, stream>>>(Wq, Wq_lsr, Weff_tmp, 0);
    eff_weight_kernel<<<2048, 256, 0, stream>>>(Wk, Wk_lsr, Weff_tmp, 512);
    eff_bias_kernel<<<8, 256, 0, stream>>>(bq, Wq_lsr, bk, Wk_lsr, bv, bcat);

    transpose1024<<<dim3(16, 16), 256, 0, stream>>>(Weff_tmp, Wcat_t);
    transpose1024<<<dim3(16, 16), 256, 0, stream>>>(Wv, Wcat_t + (size_t)1024 * 1024);

    // [Yqk | Vtmp] = x @ [Wq_eff|Wk_eff|Wv] + bcat
    gemm_bt_split<<<dim3(16, 32), 256, 0, stream>>>(
        x, Wcat_t, bcat, Yqk, Vtmp, 1024);

    vt_prep<<<dim3(32, 32), 256, 0, stream>>>(Vtmp, Vbf);
    kt_prep<<<dim3(32, 16), 256, 0, stream>>>(Yqk, Kth, Ktl);

    transpose1024<<<dim3(16, 16), 256, 0, stream>>>(Wo, Wo_t);

    flash_mfma<<<1024, 256, 0, stream>>>(Yqk, Kth, Ktl, Vbf, Oacc);

    // out = Oacc @ Wo + bo
    gemm_bt_split<<<dim3(8, 32), 256, 0, stream>>>(
        Oacc, Wo_t, bo, out, out, 1 << 30);
}

// Round 16
// 260.624 us; speedup vs baseline: 1.0397x; 1.0397x over previous
//
#include <hip/hip_runtime.h>
#include <math.h>

#define D_MODEL 1024
#define N_HEADS 16
#define D_HEAD  64
#define LSR_RANK 32
#define BATCH 2
#define SEQ 2048
#define M_TOT (BATCH*SEQ)

typedef __attribute__((ext_vector_type(8))) short short8v;
typedef __attribute__((ext_vector_type(4))) float f32x4;

static __device__ __forceinline__ ushort bfhi(float f) {
    union { float f; unsigned u; } c; c.f = f;
    return (ushort)(c.u >> 16);
}
static __device__ __forceinline__ float bff(ushort h) {
    union { unsigned u; float f; } c; c.u = ((unsigned)h) << 16;
    return c.f;
}
static __device__ __forceinline__ ushort f2bf_rn(float f) {
    union { float f; unsigned u; } c; c.f = f;
    unsigned r = c.u + 0x7FFF + ((c.u >> 16) & 1);
    return (ushort)(r >> 16);
}
static __device__ __forceinline__ void split8(const float4 a, const float4 b,
                                              short8v& h, short8v& l) {
    ushort h0 = bfhi(a.x), h1 = bfhi(a.y), h2 = bfhi(a.z), h3 = bfhi(a.w);
    ushort h4 = bfhi(b.x), h5 = bfhi(b.y), h6 = bfhi(b.z), h7 = bfhi(b.w);
    h[0] = (short)h0; h[1] = (short)h1; h[2] = (short)h2; h[3] = (short)h3;
    h[4] = (short)h4; h[5] = (short)h5; h[6] = (short)h6; h[7] = (short)h7;
    l[0] = (short)bfhi(a.x - bff(h0)); l[1] = (short)bfhi(a.y - bff(h1));
    l[2] = (short)bfhi(a.z - bff(h2)); l[3] = (short)bfhi(a.w - bff(h3));
    l[4] = (short)bfhi(b.x - bff(h4)); l[5] = (short)bfhi(b.y - bff(h5));
    l[6] = (short)bfhi(b.z - bff(h6)); l[7] = (short)bfhi(b.w - bff(h7));
}

// ---------------------------------------------------------------------------
// Weff_tmp[k][base+c] = sum_d W[k, h*64+d] * Wlsr[h, d, r]
// ---------------------------------------------------------------------------
__global__ __launch_bounds__(256) void eff_weight_kernel(
    const float* __restrict__ W, const float* __restrict__ Wlsr,
    float* __restrict__ Weff_tmp, int base)
{
    int idx = blockIdx.x * 256 + threadIdx.x;
    int k = idx >> 9;
    int c = idx & 511;
    int h = c >> 5;
    int r = c & 31;
    const float* wrow = W + (size_t)k * D_MODEL + h * D_HEAD;
    const float* lsr  = Wlsr + (size_t)h * D_HEAD * LSR_RANK + r;
    float acc = 0.f;
    #pragma unroll
    for (int d = 0; d < D_HEAD; ++d)
        acc = fmaf(wrow[d], lsr[d * LSR_RANK], acc);
    Weff_tmp[(size_t)k * 1024 + base + c] = acc;
}

__global__ __launch_bounds__(256) void eff_bias_kernel(
    const float* __restrict__ bq, const float* __restrict__ Wq_lsr,
    const float* __restrict__ bk, const float* __restrict__ Wk_lsr,
    const float* __restrict__ bv, float* __restrict__ bcat)
{
    int c = blockIdx.x * 256 + threadIdx.x;
    if (c < 1024) {
        const float* bias = (c < 512) ? bq : bk;
        const float* lsr  = (c < 512) ? Wq_lsr : Wk_lsr;
        int cc = c & 511;
        int h = cc >> 5, r = cc & 31;
        float acc = 0.f;
        #pragma unroll
        for (int d = 0; d < D_HEAD; ++d)
            acc = fmaf(bias[h * D_HEAD + d],
                       lsr[(size_t)h * D_HEAD * LSR_RANK + d * LSR_RANK + r], acc);
        bcat[c] = acc;
    } else {
        bcat[c] = bv[c - 1024];
    }
}

// ---------------------------------------------------------------------------
// 1024x1024 fp32 transpose
// ---------------------------------------------------------------------------
__global__ __launch_bounds__(256) void transpose1024(
    const float* __restrict__ in, float* __restrict__ out)
{
    __shared__ float t[64][65];
    const int tid = threadIdx.x;
    const int r0 = blockIdx.y * 64, c0 = blockIdx.x * 64;
    const int tr = tid >> 4, tc = tid & 15;
    #pragma unroll
    for (int i = 0; i < 4; ++i) {
        float4 v = *(const float4*)&in[(size_t)(r0 + tr + i * 16) * 1024 + c0 + tc * 4];
        t[tr + i * 16][tc * 4 + 0] = v.x;
        t[tr + i * 16][tc * 4 + 1] = v.y;
        t[tr + i * 16][tc * 4 + 2] = v.z;
        t[tr + i * 16][tc * 4 + 3] = v.w;
    }
    __syncthreads();
    #pragma unroll
    for (int i = 0; i < 4; ++i) {
        float4 v;
        v.x = t[tc * 4 + 0][tr + i * 16];
        v.y = t[tc * 4 + 1][tr + i * 16];
        v.z = t[tc * 4 + 2][tr + i * 16];
        v.w = t[tc * 4 + 3][tr + i * 16];
        *(float4*)&out[(size_t)(c0 + tr + i * 16) * 1024 + r0 + tc * 4] = v;
    }
}

// ---------------------------------------------------------------------------
// Split-bf16 MFMA GEMM (r9/r10-validated), 128x128 tile, BK=32.
// ---------------------------------------------------------------------------
__global__ __launch_bounds__(256) void gemm_bt_split(
    const float* __restrict__ A,
    const float* __restrict__ Bt,
    const float* __restrict__ bias,
    float* __restrict__ C0, float* __restrict__ C1, int csplit)
{
    __shared__ __align__(16) short Ah[128 * 40], Al[128 * 40];
    __shared__ __align__(16) short Bh[128 * 40], Bl[128 * 40];

    const int tid = threadIdx.x;
    const int m0 = blockIdx.y * 128, n0 = blockIdx.x * 128;
    const int wid = tid >> 6, wr = wid >> 1, wc = wid & 1;
    const int lane = tid & 63, fr = lane & 15, fq = lane >> 4;
    const int srow = tid >> 1;
    const int skq  = (tid & 1) << 4;

    float* Cw; int ncol;
    if (n0 < csplit) { Cw = C0; ncol = n0; }
    else             { Cw = C1; ncol = n0 - csplit; }

    f32x4 acc[4][4];
    #pragma unroll
    for (int i = 0; i < 4; ++i)
        #pragma unroll
        for (int j = 0; j < 4; ++j)
            acc[i][j] = (f32x4){0.f, 0.f, 0.f, 0.f};

    const float* Ag = A + (size_t)(m0 + srow) * 1024 + skq;
    const float* Bg = Bt + (size_t)(n0 + srow) * 1024 + skq;
    short* pAh = &Ah[srow * 40 + skq];
    short* pAl = &Al[srow * 40 + skq];
    short* pBh = &Bh[srow * 40 + skq];
    short* pBl = &Bl[srow * 40 + skq];

    for (int k0 = 0; k0 < 1024; k0 += 32) {
        float4 a0 = *(const float4*)(Ag + k0);
        float4 a1 = *(const float4*)(Ag + k0 + 4);
        float4 a2 = *(const float4*)(Ag + k0 + 8);
        float4 a3 = *(const float4*)(Ag + k0 + 12);
        float4 b0 = *(const float4*)(Bg + k0);
        float4 b1 = *(const float4*)(Bg + k0 + 4);
        float4 b2 = *(const float4*)(Bg + k0 + 8);
        float4 b3 = *(const float4*)(Bg + k0 + 12);
        short8v h, l;
        split8(a0, a1, h, l);
        *(short8v*)pAh = h;  *(short8v*)pAl = l;
        split8(a2, a3, h, l);
        *(short8v*)(pAh + 8) = h;  *(short8v*)(pAl + 8) = l;
        split8(b0, b1, h, l);
        *(short8v*)pBh = h;  *(short8v*)pBl = l;
        split8(b2, b3, h, l);
        *(short8v*)(pBh + 8) = h;  *(short8v*)(pBl + 8) = l;
        __syncthreads();

        short8v afh[4], afl[4], bfh[4], bfl[4];
        #pragma unroll
        for (int fi = 0; fi < 4; ++fi) {
            const int ar = wr * 64 + fi * 16 + fr;
            afh[fi] = *(const short8v*)&Ah[ar * 40 + fq * 8];
            afl[fi] = *(const short8v*)&Al[ar * 40 + fq * 8];
        }
        #pragma unroll
        for (int bj = 0; bj < 4; ++bj) {
            const int br = wc * 64 + bj * 16 + fr;
            bfh[bj] = *(const short8v*)&Bh[br * 40 + fq * 8];
            bfl[bj] = *(const short8v*)&Bl[br * 40 + fq * 8];
        }
        #pragma unroll
        for (int fi = 0; fi < 4; ++fi) {
            #pragma unroll
            for (int bj = 0; bj < 4; ++bj) {
                acc[fi][bj] = __builtin_amdgcn_mfma_f32_16x16x32_bf16(
                    afh[fi], bfh[bj], acc[fi][bj], 0, 0, 0);
                acc[fi][bj] = __builtin_amdgcn_mfma_f32_16x16x32_bf16(
                    afh[fi], bfl[bj], acc[fi][bj], 0, 0, 0);
                acc[fi][bj] = __builtin_amdgcn_mfma_f32_16x16x32_bf16(
                    afl[fi], bfh[bj], acc[fi][bj], 0, 0, 0);
            }
        }
        __syncthreads();
    }

    #pragma unroll
    for (int fi = 0; fi < 4; ++fi) {
        #pragma unroll
        for (int bj = 0; bj < 4; ++bj) {
            const int r = m0 + wr * 64 + fi * 16 + fq * 4;
            const int c = ncol + wc * 64 + bj * 16 + fr;
            const float bv_ = bias[n0 - ncol + c];
            #pragma unroll
            for (int j = 0; j < 4; ++j)
                Cw[(size_t)(r + j) * 1024 + c] = acc[fi][bj][j] + bv_;
        }
    }
}

// ---------------------------------------------------------------------------
// K pre-split into B-frag-ready layout: Kth/Ktl [bh][2048 t][32 r] bf16.
// ---------------------------------------------------------------------------
__global__ __launch_bounds__(256) void kt_prep(
    const float* __restrict__ Yqk,
    short* __restrict__ Kth, short* __restrict__ Ktl)
{
    const int bh = blockIdx.x;
    const int b = bh >> 4, h = bh & 15;
    const int t0 = blockIdx.y * 128;
    const int tid = threadIdx.x;
    const int tl = tid >> 1, half = tid & 1;
    const float* src = Yqk + (size_t)(b * SEQ + t0 + tl) * 1024 + 512 + h * 32 + half * 16;
    short8v h0, l0, h1, l1;
    split8(((const float4*)src)[0], ((const float4*)src)[1], h0, l0);
    split8(((const float4*)src)[2], ((const float4*)src)[3], h1, l1);
    short* oh = Kth + ((size_t)bh * 2048 + t0 + tl) * 32 + half * 16;
    short* ol = Ktl + ((size_t)bh * 2048 + t0 + tl) * 32 + half * 16;
    *(short8v*)oh = h0;  *(short8v*)(oh + 8) = h1;
    *(short8v*)ol = l0;  *(short8v*)(ol + 8) = l1;
}

// ---------------------------------------------------------------------------
// V transpose + bf16-rn: Vtmp[4096][1024] -> Vbf [bh][64 d][2048 t]
// ---------------------------------------------------------------------------
__global__ __launch_bounds__(256) void vt_prep(
    const float* __restrict__ Vtmp, short* __restrict__ Vbf)
{
    __shared__ float t[64][68];
    const int bh = blockIdx.x;
    const int b = bh >> 4, h = bh & 15;
    const int t0 = blockIdx.y * 64;
    const int tid = threadIdx.x;
    {
        const int tl = tid >> 2, sg = tid & 3;
        const float* vp = Vtmp + (size_t)(b * SEQ + t0 + tl) * 1024 + h * 64 + sg * 16;
        #pragma unroll
        for (int i = 0; i < 4; ++i)
            *(float4*)&t[tl][sg * 16 + i * 4] = *(const float4*)(vp + i * 4);
    }
    __syncthreads();
    {
        const int d = tid >> 2, sg = tid & 3;
        short8v h0, h1;
        #pragma unroll
        for (int i = 0; i < 8; ++i) {
            h0[i] = (short)f2bf_rn(t[sg * 16 + i][d]);
            h1[i] = (short)f2bf_rn(t[sg * 16 + 8 + i][d]);
        }
        short* oh = Vbf + ((size_t)bh * 64 + d) * 2048 + t0 + sg * 16;
        *(short8v*)oh = h0;  *(short8v*)(oh + 8) = h1;
    }
}

// ---------------------------------------------------------------------------
// MFMA flash attention v7 = v6 with the LDS aliasing race FIXED.
// r15 failure: the parity-exchange region `ex` aliased the per-wave P
// buffers; p=1 waves finished their loop and overwrote p=0 waves' P
// buffers while p=0 was still mid-loop (no barrier can separate divergent-
// trip-count loops) -> corrupted P -> inf*0 -> NaN. Fix: `ex` is its OWN
// __shared__ array (no alias). LDS = 17.4K (P) + 28.7K (ex) = 46K ->
// 3 blocks/CU x 8 waves = 24 waves/CU cap (was 16 at r13).
// ---------------------------------------------------------------------------
#define P_LD  68
#define MASKVAL (-1e30f)

__global__ __launch_bounds__(512) void flash_mfma(
    const float* __restrict__ Yqk,   // [4096][1024]: q_lr(512) | k_lr(512)
    const short* __restrict__ Kth, const short* __restrict__ Ktl,
    const short* __restrict__ Vbf,   // [32][64][2048]
    float* __restrict__ O)           // [4096][1024] (B,T,H,Dh)
{
    const float scale = 0.1767766952966369f;  // 1/sqrt(32)
    const int L = blockIdx.x;
    const int bh = L & 31;
    const int qt = 31 - (L >> 5);              // LPT: big tiles first
    const int b = bh >> 4, h = bh & 15;
    const int tid = threadIdx.x;
    const int w = tid >> 6;                    // 0..7
    const int g = w & 3;                       // q-row group (g*16..+16)
    const int p = w >> 2;                      // jt parity
    const int lane = tid & 63;
    const int fr = lane & 15, fq = lane >> 4;

    __shared__ __align__(16) short Pall[8][16 * P_LD];   // 17408 B
    __shared__ __align__(16) float ex[4 * 64 * 28];      // 28672 B (separate!)
    short* Pw = &Pall[w][0];

    short8v aqh, aql;
    {
        const float* qp = Yqk + (size_t)(b * SEQ + qt * 64 + g * 16 + fr) * 1024
                          + h * 32 + fq * 8;
        split8(*(const float4*)qp, *(const float4*)(qp + 4), aqh, aql);
    }

    f32x4 acc0 = {0,0,0,0}, acc1 = {0,0,0,0}, acc2 = {0,0,0,0}, acc3 = {0,0,0,0};
    float m_[4], l_[4];
    #pragma unroll
    for (int r = 0; r < 4; ++r) { m_[r] = MASKVAL; l_[r] = 0.f; }

    const short* kb_h = Kth + (size_t)bh * 2048 * 32;
    const short* kb_l = Ktl + (size_t)bh * 2048 * 32;
    const short* vb   = Vbf + (size_t)bh * 64 * 2048;
    const int kidx = fr * 32 + fq * 8;
    const int vrow = fr * 2048 + fq * 8;

    for (int jt = p; jt <= qt; jt += 2) {
        // ---- load cluster ----
        const short* kp_h = kb_h + (size_t)jt * 64 * 32;
        const short* kp_l = kb_l + (size_t)jt * 64 * 32;
        short8v kh0 = *(const short8v*)&kp_h[kidx];
        short8v kh1 = *(const short8v*)&kp_h[kidx + 512];
        short8v kh2 = *(const short8v*)&kp_h[kidx + 1024];
        short8v kh3 = *(const short8v*)&kp_h[kidx + 1536];
        short8v kl0 = *(const short8v*)&kp_l[kidx];
        short8v kl1 = *(const short8v*)&kp_l[kidx + 512];
        short8v kl2 = *(const short8v*)&kp_l[kidx + 1024];
        short8v kl3 = *(const short8v*)&kp_l[kidx + 1536];
        const short* vp = vb + vrow + jt * 64;
        short8v v00 = *(const short8v*)&vp[0];
        short8v v01 = *(const short8v*)&vp[32];
        short8v v10 = *(const short8v*)&vp[16 * 2048];
        short8v v11 = *(const short8v*)&vp[16 * 2048 + 32];
        short8v v20 = *(const short8v*)&vp[32 * 2048];
        short8v v21 = *(const short8v*)&vp[32 * 2048 + 32];
        short8v v30 = *(const short8v*)&vp[48 * 2048];
        short8v v31 = *(const short8v*)&vp[48 * 2048 + 32];

        // ---- S = Q K^T (split-bf16) ----
        f32x4 s0 = {0,0,0,0}, s1 = {0,0,0,0}, s2 = {0,0,0,0}, s3 = {0,0,0,0};
        s0 = __builtin_amdgcn_mfma_f32_16x16x32_bf16(aqh, kh0, s0, 0, 0, 0);
        s0 = __builtin_amdgcn_mfma_f32_16x16x32_bf16(aqh, kl0, s0, 0, 0, 0);
        s0 = __builtin_amdgcn_mfma_f32_16x16x32_bf16(aql, kh0, s0, 0, 0, 0);
        s1 = __builtin_amdgcn_mfma_f32_16x16x32_bf16(aqh, kh1, s1, 0, 0, 0);
        s1 = __builtin_amdgcn_mfma_f32_16x16x32_bf16(aqh, kl1, s1, 0, 0, 0);
        s1 = __builtin_amdgcn_mfma_f32_16x16x32_bf16(aql, kh1, s1, 0, 0, 0);
        s2 = __builtin_amdgcn_mfma_f32_16x16x32_bf16(aqh, kh2, s2, 0, 0, 0);
        s2 = __builtin_amdgcn_mfma_f32_16x16x32_bf16(aqh, kl2, s2, 0, 0, 0);
        s2 = __builtin_amdgcn_mfma_f32_16x16x32_bf16(aql, kh2, s2, 0, 0, 0);
        s3 = __builtin_amdgcn_mfma_f32_16x16x32_bf16(aqh, kh3, s3, 0, 0, 0);
        s3 = __builtin_amdgcn_mfma_f32_16x16x32_bf16(aqh, kl3, s3, 0, 0, 0);
        s3 = __builtin_amdgcn_mfma_f32_16x16x32_bf16(aql, kh3, s3, 0, 0, 0);

        s0 *= scale; s1 *= scale; s2 *= scale; s3 *= scale;

        if (jt == qt) {   // only the wave with p == (qt&1) reaches this
            #pragma unroll
            for (int r = 0; r < 4; ++r) {
                const int q_l = g * 16 + fq * 4 + r;
                s0[r] = (fr      <= q_l) ? s0[r] : MASKVAL;
                s1[r] = (16 + fr <= q_l) ? s1[r] : MASKVAL;
                s2[r] = (32 + fr <= q_l) ? s2[r] : MASKVAL;
                s3[r] = (48 + fr <= q_l) ? s3[r] : MASKVAL;
            }
        }

        float al[4];
        #pragma unroll
        for (int r = 0; r < 4; ++r) {
            float mt = fmaxf(fmaxf(s0[r], s1[r]), fmaxf(s2[r], s3[r]));
            mt = fmaxf(mt, __shfl_xor(mt, 1));
            mt = fmaxf(mt, __shfl_xor(mt, 2));
            mt = fmaxf(mt, __shfl_xor(mt, 4));
            mt = fmaxf(mt, __shfl_xor(mt, 8));
            const float mnew = fmaxf(m_[r], mt);
            al[r] = __expf(m_[r] - mnew);
            m_[r] = mnew;
            s0[r] = __expf(s0[r] - mnew);
            s1[r] = __expf(s1[r] - mnew);
            s2[r] = __expf(s2[r] - mnew);
            s3[r] = __expf(s3[r] - mnew);
            float ps = s0[r] + s1[r] + s2[r] + s3[r];
            ps += __shfl_xor(ps, 1);
            ps += __shfl_xor(ps, 2);
            ps += __shfl_xor(ps, 4);
            ps += __shfl_xor(ps, 8);
            l_[r] = l_[r] * al[r] + ps;
        }

        #pragma unroll
        for (int r = 0; r < 4; ++r) {
            const int prow = fq * 4 + r;
            Pw[prow * P_LD +      fr] = (short)f2bf_rn(s0[r]);
            Pw[prow * P_LD + 16 + fr] = (short)f2bf_rn(s1[r]);
            Pw[prow * P_LD + 32 + fr] = (short)f2bf_rn(s2[r]);
            Pw[prow * P_LD + 48 + fr] = (short)f2bf_rn(s3[r]);
        }
        #pragma unroll
        for (int r = 0; r < 4; ++r) {
            acc0[r] *= al[r]; acc1[r] *= al[r];
            acc2[r] *= al[r]; acc3[r] *= al[r];
        }
        short8v pa0 = *(const short8v*)&Pw[fr * P_LD + fq * 8];
        short8v pa1 = *(const short8v*)&Pw[fr * P_LD + 32 + fq * 8];

        acc0 = __builtin_amdgcn_mfma_f32_16x16x32_bf16(pa0, v00, acc0, 0, 0, 0);
        acc0 = __builtin_amdgcn_mfma_f32_16x16x32_bf16(pa1, v01, acc0, 0, 0, 0);
        acc1 = __builtin_amdgcn_mfma_f32_16x16x32_bf16(pa0, v10, acc1, 0, 0, 0);
        acc1 = __builtin_amdgcn_mfma_f32_16x16x32_bf16(pa1, v11, acc1, 0, 0, 0);
        acc2 = __builtin_amdgcn_mfma_f32_16x16x32_bf16(pa0, v20, acc2, 0, 0, 0);
        acc2 = __builtin_amdgcn_mfma_f32_16x16x32_bf16(pa1, v21, acc2, 0, 0, 0);
        acc3 = __builtin_amdgcn_mfma_f32_16x16x32_bf16(pa0, v30, acc3, 0, 0, 0);
        acc3 = __builtin_amdgcn_mfma_f32_16x16x32_bf16(pa1, v31, acc3, 0, 0, 0);
    }

    // ---- parity merge: p=1 publishes, p=0 combines and writes out ----
    if (p == 1) {
        float* e = ex + ((g << 6) + lane) * 28;
        *(f32x4*)(e +  0) = acc0;
        *(f32x4*)(e +  4) = acc1;
        *(f32x4*)(e +  8) = acc2;
        *(f32x4*)(e + 12) = acc3;
        *(f32x4*)(e + 16) = (f32x4){m_[0], m_[1], m_[2], m_[3]};
        *(f32x4*)(e + 20) = (f32x4){l_[0], l_[1], l_[2], l_[3]};
    }
    __syncthreads();
    if (p == 0) {
        const float* e = ex + ((g << 6) + lane) * 28;
        f32x4 b0 = *(const f32x4*)(e +  0);
        f32x4 b1 = *(const f32x4*)(e +  4);
        f32x4 b2 = *(const f32x4*)(e +  8);
        f32x4 b3 = *(const f32x4*)(e + 12);
        f32x4 m1 = *(const f32x4*)(e + 16);
        f32x4 l1 = *(const f32x4*)(e + 20);
        #pragma unroll
        for (int r = 0; r < 4; ++r) {
            const float mm = fmaxf(m_[r], m1[r]);
            const float a0 = __expf(m_[r] - mm);   // p=0 always has >=1 tile
            const float a1 = __expf(m1[r] - mm);   // 0 if p=1 wave was empty
            const float inv = 1.f / (l_[r] * a0 + l1[r] * a1);
            const int trow = qt * 64 + g * 16 + fq * 4 + r;
            float* op = O + (size_t)(b * SEQ + trow) * 1024 + h * 64;
            op[     fr] = (acc0[r] * a0 + b0[r] * a1) * inv;
            op[16 + fr] = (acc1[r] * a0 + b1[r] * a1) * inv;
            op[32 + fr] = (acc2[r] * a0 + b2[r] * a1) * inv;
            op[48 + fr] = (acc3[r] * a0 + b3[r] * a1) * inv;
        }
    }
}

// ---------------------------------------------------------------------------
extern "C" void kernel_launch(void* const* d_in, const int* in_sizes, int n_in,
                              void* d_out, int out_size, void* d_ws, size_t ws_size,
                              hipStream_t stream)
{
    const float* x      = (const float*)d_in[0];
    const float* Wq     = (const float*)d_in[1];
    const float* bq     = (const float*)d_in[2];
    const float* Wk     = (const float*)d_in[3];
    const float* bk     = (const float*)d_in[4];
    const float* Wv     = (const float*)d_in[5];
    const float* bv     = (const float*)d_in[6];
    const float* Wo     = (const float*)d_in[7];
    const float* bo     = (const float*)d_in[8];
    const float* Wq_lsr = (const float*)d_in[9];
    const float* Wk_lsr = (const float*)d_in[10];
    float* out = (float*)d_out;

    // workspace (floats/shorts), ~56 MB
    float* ws     = (float*)d_ws;
    float* Wcat_t = ws;                                    // 2M f (8 MB)
    float* bcat   = Wcat_t + (size_t)2048 * 1024;          // 2048
    float* Yqk    = bcat + 2048;                           // 4M f (16 MB)
    float* Vtmp   = Yqk + (size_t)M_TOT * 1024;            // 4M f (16 MB)
    short* Vbf    = (short*)(Vtmp + (size_t)M_TOT * 1024); // 4M s (8 MB)
    short* Kth    = Vbf + (size_t)32 * 64 * 2048;          // 2M s (4 MB)
    short* Ktl    = Kth + (size_t)32 * 2048 * 32;          // 2M s (4 MB)
    float* Weff_tmp = (float*)Vbf;   // alias: dead before vt_prep writes Vbf
    float* Oacc   = Vtmp;            // alias: fp32 V dead after vt_prep
    float* Wo_t   = Wcat_t;          // alias: Wcat_t dead after proj gemm

    eff_weight_kernel<<<2048, 256, 0, stream>>>(Wq, Wq_lsr, Weff_tmp, 0);
    eff_weight_kernel<<<2048, 256, 0, stream>>>(Wk, Wk_lsr, Weff_tmp, 512);
    eff_bias_kernel<<<8, 256, 0, stream>>>(bq, Wq_lsr, bk, Wk_lsr, bv, bcat);

    transpose1024<<<dim3(16, 16), 256, 0, stream>>>(Weff_tmp, Wcat_t);
    transpose1024<<<dim3(16, 16), 256, 0, stream>>>(Wv, Wcat_t + (size_t)1024 * 1024);

    // [Yqk | Vtmp] = x @ [Wq_eff|Wk_eff|Wv] + bcat
    gemm_bt_split<<<dim3(16, 32), 256, 0, stream>>>(
        x, Wcat_t, bcat, Yqk, Vtmp, 1024);

    vt_prep<<<dim3(32, 32), 256, 0, stream>>>(Vtmp, Vbf);
    kt_prep<<<dim3(32, 16), 256, 0, stream>>>(Yqk, Kth, Ktl);

    transpose1024<<<dim3(16, 16), 256, 0, stream>>>(Wo, Wo_t);

    flash_mfma<<<1024, 512, 0, stream>>>(Yqk, Kth, Ktl, Vbf, Oacc);

    // out = Oacc @ Wo + bo
    gemm_bt_split<<<dim3(8, 32), 256, 0, stream>>>(
        Oacc, Wo_t, bo, out, out, 1 << 30);
}